// Round 11
// baseline (999.769 us; speedup 1.0000x reference)
//
#include <hip/hip_runtime.h>
#include <hip/hip_bf16.h>
#include <cstdint>

// ---------------------------------------------------------------------------
// KAN 2-layer forward as two bf16 MFMA GEMMs (fp32 output).
// Round-11 (vs r10 @994us, BK=64 null):
//  * GEMM = faithful m201 phase schedule: BK=32, 3 LDS buffers, 2 phases/tile,
//    each phase {ds_read frags | 2xGLD16 stage(t+2)->q2 | barrier |
//    lgkmcnt(0)+sched_barrier(0) | setprio(1) 16 MFMA setprio(0) | barrier}.
//    Counted vmcnt(L) once per tile (never 0 in loop): outstanding=2L ->
//    drains exactly tile t+1 (FIFO, m135). WAR: q2 holds tile t-1 whose
//    ds_reads all retired (lgkm-waited) before t-1's closing barrier.
//  * kperm i-block-64: k=(i/64)*576+c*64+(i%64) in prep_w+expand_aug.
//    Channel stores become full aligned 128B lines (was 64B half-line
//    segments at 576B stride -> L2 read-modify-write; aux stuck ~368us
//    vs 136us ideal across 4 rewrites). GEMM k-order-agnostic.
// Proven, kept: bijective LDS swizzle ((row>>1)&3)<<4 both-sides (0
// conflicts), XCD bijective block swizzle, setprio, epilogue math.
// ws: h1 fp32 [0,64MiB) | W bf16 [64,100MiB) | Aug bf16 [100MiB,...)
// ---------------------------------------------------------------------------

typedef __attribute__((ext_vector_type(8))) short short8;
typedef __attribute__((ext_vector_type(4))) short short4v;
typedef __attribute__((ext_vector_type(4))) float f32x4;

#define GLD16(gp, lp)                                                          \
  __builtin_amdgcn_global_load_lds(                                           \
      (const __attribute__((address_space(1))) unsigned int*)(gp),             \
      (__attribute__((address_space(3))) unsigned int*)(lp), 16, 0, 0)

__device__ __forceinline__ unsigned short f2bf(float f) {
  __hip_bfloat16 h = __float2bfloat16(f);
  return *reinterpret_cast<unsigned short*>(&h);
}

// ---- pack weights: W[o, kperm(c,i)], kperm = (i/64)*576 + c*64 + (i%64) ----
__global__ void prep_w(const float* __restrict__ coef, const float* __restrict__ sb,
                       const float* __restrict__ sp, const float* __restrict__ mask,
                       __hip_bfloat16* __restrict__ W, int O, int I) {
  long idx = (long)blockIdx.x * blockDim.x + threadIdx.x;
  long total = (long)O * (I >> 2);
  if (idx >= total) return;
  int qtr = I >> 2;
  int iq = (int)(idx % qtr);
  int o  = (int)(idx / qtr);
  int i  = iq << 2;
  size_t oi = (size_t)o * I + i;
  float4 mk4 = *(const float4*)(mask + oi);
  float4 sp4 = *(const float4*)(sp + oi);
  float4 sb4 = *(const float4*)(sb + oi);
  float spm[4] = {sp4.x * mk4.x, sp4.y * mk4.y, sp4.z * mk4.z, sp4.w * mk4.w};
  float cf[4][8];
  const float4* cp = (const float4*)(coef + oi * 8);
#pragma unroll
  for (int e = 0; e < 4; e++) {
    float4 a = cp[e * 2], b = cp[e * 2 + 1];
    cf[e][0] = a.x; cf[e][1] = a.y; cf[e][2] = a.z; cf[e][3] = a.w;
    cf[e][4] = b.x; cf[e][5] = b.y; cf[e][6] = b.z; cf[e][7] = b.w;
  }
  __hip_bfloat16* base = W + (size_t)o * (size_t)(9 * I) + (i >> 6) * 576 + (i & 63);
#pragma unroll
  for (int c = 0; c < 8; c++) {
    short4v pk;
#pragma unroll
    for (int e = 0; e < 4; e++) pk[e] = (short)f2bf(cf[e][c] * spm[e]);
    *(short4v*)(base + c * 64) = pk;
  }
  short4v ps;
  ps[0] = (short)f2bf(sb4.x * mk4.x); ps[1] = (short)f2bf(sb4.y * mk4.y);
  ps[2] = (short)f2bf(sb4.z * mk4.z); ps[3] = (short)f2bf(sb4.w * mk4.w);
  *(short4v*)(base + 8 * 64) = ps;
}

// ---- expand activations: Aug[b, kperm(c,i)], 8 elems/thread ---------------
__device__ __forceinline__ void basis8(float x, float* w, int& j) {
  float u  = (x + 2.2f) * 2.5f;
  float fj = floorf(u);
  j = (int)fj;
  float t  = u - fj;
  float omt = 1.0f - t;
  float t2 = t * t, t3 = t2 * t;
  w[0] = omt * omt * omt * (1.0f / 6.0f);                              // d==3
  w[1] = (3.0f * t3 - 6.0f * t2 + 4.0f) * (1.0f / 6.0f);               // d==2
  w[2] = (-3.0f * t3 + 3.0f * t2 + 3.0f * t + 1.0f) * (1.0f / 6.0f);   // d==1
  w[3] = t3 * (1.0f / 6.0f);                                           // d==0
}

__global__ void expand_aug(const float* __restrict__ src,
                           __hip_bfloat16* __restrict__ aug,
                           long totalOcts, int I) {
  long idx = (long)blockIdx.x * blockDim.x + threadIdx.x;
  if (idx >= totalOcts) return;
  int  oct = I >> 3;
  int  io = (int)(idx % oct);
  long b  = idx / oct;
  int  i  = io << 3;            // octet within one 64-block (8 | 64)
  const float* sp = src + b * (size_t)I + i;
  float4 xa = *(const float4*)sp;
  float4 xb = *(const float4*)(sp + 4);
  float xv[8] = {xa.x, xa.y, xa.z, xa.w, xb.x, xb.y, xb.z, xb.w};

  float w[8][4], s[8];
  int   j[8];
#pragma unroll
  for (int e = 0; e < 8; e++) {
    float xe = xv[e];
    s[e] = xe / (1.0f + __expf(-xe));
    basis8(xe, w[e], j[e]);
  }

  __hip_bfloat16* base = aug + b * (size_t)(9 * I) + (i >> 6) * 576 + (i & 63);
#pragma unroll
  for (int c = 0; c < 8; c++) {
    short8 pk;
#pragma unroll
    for (int e = 0; e < 8; e++) {
      int d = j[e] - c;
      float v = 0.0f;
      v = (d == 0) ? w[e][3] : v;
      v = (d == 1) ? w[e][2] : v;
      v = (d == 2) ? w[e][1] : v;
      v = (d == 3) ? w[e][0] : v;
      pk[e] = (short)f2bf(v);
    }
    *(short8*)(base + c * 64) = pk;
  }
  short8 ps;
#pragma unroll
  for (int e = 0; e < 8; e++) ps[e] = (short)f2bf(s[e]);
  *(short8*)(base + 8 * 64) = ps;
}

// ---- m201-style phased GEMM: C = A*Bw^T + bias, fp32 out ------------------
// BM=256 x BN (256/128), BK=32, 8 waves 2Mx4N (per-wave 128 x BN/4), 3 bufs.
// LDS rows 64B; elem (row,kbyte) at kbyte ^ (((row>>1)&3)<<4); pre-swizzled
// global source (rule 21 both-sides; 0 conflicts verified r6).
template <int BN>
__global__ __launch_bounds__(512, 2) void gemmP(
    const __hip_bfloat16* __restrict__ A, const __hip_bfloat16* __restrict__ Bw,
    const float* __restrict__ bias, float* __restrict__ Cout, int N, int K) {
  constexpr int WN   = BN / 4;
  constexpr int NREP = BN / 64;
  constexpr int BUFB = 16384 + BN * 64;   // A 16KB + B
  constexpr int L    = 2 + BN / 128;      // GLD16/tile/thread: 4 (256), 3 (128)
  __shared__ __attribute__((aligned(16))) char lds[3 * BUFB];

  const int t = threadIdx.x;
  const int w = t >> 6, l = t & 63;
  const int wr = w >> 2, wc = w & 3;
  const int lr = l & 15;
  const int kbs = ((l >> 4) * 16) ^ (((lr >> 1) & 3) << 4);

  unsigned nwg = gridDim.x * gridDim.y;
  unsigned lin = blockIdx.y * gridDim.x + blockIdx.x;
  unsigned swz = (lin & 7) * (nwg >> 3) + (lin >> 3);
  unsigned bx = swz % gridDim.x, by = swz / gridDim.x;
  size_t brow = (size_t)by * 256, bcol = (size_t)bx * BN;

  f32x4 acc[8][NREP];
#pragma unroll
  for (int m = 0; m < 8; m++)
#pragma unroll
    for (int n = 0; n < NREP; n++) acc[m][n] = (f32x4){0.f, 0.f, 0.f, 0.f};

  const int srow  = t >> 2;                                     // 0..127
  const int scolb = ((t & 3) * 16) ^ (((srow >> 1) & 3) << 4);
  const __hip_bfloat16* gA0 = A + (brow + srow) * (size_t)K + (scolb >> 1);
  const __hip_bfloat16* gA1 = gA0 + (size_t)128 * K;
  const __hip_bfloat16* gB0 = Bw + (bcol + srow) * (size_t)K + (scolb >> 1);
  const __hip_bfloat16* gB1 = gB0 + (size_t)128 * K;            // BN=256 only

  char* ldsp = (char*)lds;
  const int paOff = (wr * 128 + lr) * 64 + kbs;
  const int pbOff = 16384 + (wc * WN + lr) * 64 + kbs;

  auto SA = [&](int kt, int q) {
    char* bp = ldsp + q * BUFB;
    GLD16(gA0 + (kt << 5), bp + w * 1024);
    GLD16(gA1 + (kt << 5), bp + 8192 + w * 1024);
  };
  auto SB = [&](int kt, int q) {
    char* bp = ldsp + q * BUFB + 16384;
    GLD16(gB0 + (kt << 5), bp + w * 1024);
    if constexpr (BN == 256) GLD16(gB1 + (kt << 5), bp + 8192 + w * 1024);
  };
  auto VMCNT_L = [&]() {
    if constexpr (BN == 256) asm volatile("s_waitcnt vmcnt(4)" ::: "memory");
    else                     asm volatile("s_waitcnt vmcnt(3)" ::: "memory");
  };

  // prologue: tiles 0,1 into bufs 0,1; drain tile 0 (counted), publish
  SA(0, 0); SB(0, 0);
  SA(1, 1); SB(1, 1);
  VMCNT_L();
  __builtin_amdgcn_s_barrier();

  const int NT = K >> 5;   // 288 (L0) / 576 (L1)
  int cur = 0;
  for (int tt = 0; tt < NT; ++tt) {
    int q2 = cur + 2; if (q2 >= 3) q2 -= 3;
    const char* pa = ldsp + cur * BUFB + paOff;
    const char* pb = ldsp + cur * BUFB + pbOff;
    short8 bq[NREP], aq[4];
    // ---- phase 0: reads | stage A(t+2) | bar | lgkm | MFMA m0-3 | bar ----
#pragma unroll
    for (int n = 0; n < NREP; n++) bq[n] = *(const short8*)(pb + n * 1024);
#pragma unroll
    for (int m = 0; m < 4; m++) aq[m] = *(const short8*)(pa + m * 1024);
    if (tt + 2 < NT) SA(tt + 2, q2);
    __builtin_amdgcn_s_barrier();
    asm volatile("s_waitcnt lgkmcnt(0)" ::: "memory");
    __builtin_amdgcn_sched_barrier(0);
    __builtin_amdgcn_s_setprio(1);
#pragma unroll
    for (int m = 0; m < 4; m++)
#pragma unroll
      for (int n = 0; n < NREP; n++)
        acc[m][n] = __builtin_amdgcn_mfma_f32_16x16x32_bf16(aq[m], bq[n], acc[m][n], 0, 0, 0);
    __builtin_amdgcn_s_setprio(0);
    __builtin_amdgcn_s_barrier();
    // ---- phase 1: reads | stage B(t+2) | vmcnt(L) | bar | lgkm | MFMA ----
#pragma unroll
    for (int m = 0; m < 4; m++) aq[m] = *(const short8*)(pa + (m + 4) * 1024);
    if (tt + 2 < NT) {
      SB(tt + 2, q2);
      VMCNT_L();                     // 2L outstanding -> drains tile t+1
    } else if (tt + 1 < NT) {
      asm volatile("s_waitcnt vmcnt(0)" ::: "memory");   // tail drain
    }
    __builtin_amdgcn_s_barrier();
    asm volatile("s_waitcnt lgkmcnt(0)" ::: "memory");
    __builtin_amdgcn_sched_barrier(0);
    __builtin_amdgcn_s_setprio(1);
#pragma unroll
    for (int m = 0; m < 4; m++)
#pragma unroll
      for (int n = 0; n < NREP; n++)
        acc[m + 4][n] = __builtin_amdgcn_mfma_f32_16x16x32_bf16(aq[m], bq[n], acc[m + 4][n], 0, 0, 0);
    __builtin_amdgcn_s_setprio(0);
    __builtin_amdgcn_s_barrier();
    cur = cur + 1; if (cur == 3) cur = 0;
  }

  // epilogue
  const int orow = (l >> 4) << 2;
#pragma unroll
  for (int n = 0; n < NREP; n++) {
    size_t col = bcol + (size_t)wc * WN + n * 16 + lr;
    float bv = bias[col];
#pragma unroll
    for (int m = 0; m < 8; m++) {
      size_t row = brow + (size_t)wr * 128 + m * 16 + orow;
#pragma unroll
      for (int r = 0; r < 4; r++)
        Cout[(row + r) * (size_t)N + col] = acc[m][n][r] + bv;
    }
  }
}

// ---------------------------------------------------------------------------
extern "C" void kernel_launch(void* const* d_in, const int* in_sizes, int n_in,
                              void* d_out, int out_size, void* d_ws, size_t ws_size,
                              hipStream_t stream) {
  const float* x     = (const float*)d_in[0];
  const float* coef0 = (const float*)d_in[1];
  const float* sb0   = (const float*)d_in[2];
  const float* sp0   = (const float*)d_in[3];
  const float* mask0 = (const float*)d_in[4];
  const float* bias0 = (const float*)d_in[5];
  const float* coef1 = (const float*)d_in[6];
  const float* sb1   = (const float*)d_in[7];
  const float* sp1   = (const float*)d_in[8];
  const float* mask1 = (const float*)d_in[9];
  const float* bias1 = (const float*)d_in[10];
  float* out = (float*)d_out;

  const int B = 8192, D0 = 1024, D1 = 2048, D2 = 1024;
  const int K0 = 9 * D0;   // 9216
  const int K1 = 9 * D1;   // 18432

  char* ws = (char*)d_ws;
  float*          h1  = (float*)ws;                                   // 64 MiB
  __hip_bfloat16* W   = (__hip_bfloat16*)(ws + (size_t)67108864);     // 36 MiB
  __hip_bfloat16* Aug = (__hip_bfloat16*)(ws + (size_t)104857600);

  const bool fullL1 = ws_size >= (size_t)104857600 + (size_t)B * K1 * 2;

  // ---- layer 0: full batch ----
  {
    long nt = (long)D1 * (D0 / 4);
    prep_w<<<(unsigned)((nt + 255) / 256), 256, 0, stream>>>(coef0, sb0, sp0, mask0, W, D1, D0);
    long no = (long)B * (D0 / 8);
    expand_aug<<<(unsigned)((no + 255) / 256), 256, 0, stream>>>(x, Aug, no, D0);
    dim3 g0(D1 / 256, B / 256);  // (8, 32) = 256 blocks
    gemmP<256><<<g0, 512, 0, stream>>>(Aug, W, bias0, h1, D1, K0);
  }

  // ---- layer 1 ----
  {
    long nt = (long)D2 * (D1 / 4);
    prep_w<<<(unsigned)((nt + 255) / 256), 256, 0, stream>>>(coef1, sb1, sp1, mask1, W, D2, D1);
    const int CH = fullL1 ? B : 4096;
    for (int ch = 0; ch < B / CH; ch++) {
      long no = (long)CH * (D1 / 8);
      expand_aug<<<(unsigned)((no + 255) / 256), 256, 0, stream>>>(
          h1 + (size_t)ch * CH * D1, Aug, no, D1);
      dim3 g1(D2 / 128, CH / 256);  // full: (8, 32) = 256 blocks
      gemmP<128><<<g1, 512, 0, stream>>>(Aug, W, bias1,
                                         out + (size_t)ch * CH * D2, D2, K1);
    }
  }
}